// Round 1
// baseline (202.756 us; speedup 1.0000x reference)
//
#include <hip/hip_runtime.h>
#include <cstdint>

#define GH 10
#define GW 10

__global__ __launch_bounds__(256, 1) void custom_loss_kernel(
    const float* __restrict__ result,
    const int* __restrict__ points,
    float* __restrict__ out,
    int B)
{
    const int t = blockIdx.x * blockDim.x + threadIdx.x;
    float loss = 0.f;
    if (t < B) {
        const float* __restrict__ r = result + (size_t)t * 100;
        const int4 p = ((const int4*)points)[t];
        const int p0y = p.x, p0x = p.y, p1y = p.z, p1x = p.w;
        const int base = abs(p0y - p1y) + abs(p0x - p1x);
        const int idx0 = p0y * GW + p0x;
        const int idx1 = p1y * GW + p1x;

        // delta(y,x) = ady[y] + adx[x]  (both >= 0)
        int ady[GH], adx[GW];
#pragma unroll
        for (int i = 0; i < GH; ++i) {
            ady[i] = abs(i - p0y) + abs(i - p1y) - abs(p0y - p1y);
            adx[i] = abs(i - p0x) + abs(i - p1x) - abs(p0x - p1x);
        }

        float rv[100];
        uint64_t mlo = 0, mhi = 0;        // round(r)==1 mask, 10 bits/row
        float sum_all = 0.f, single_cell = 0.f, rs = 0.f, re = 0.f;
#pragma unroll
        for (int i = 0; i < 25; ++i) {
            const float4 v = ((const float4*)r)[i];
            const float vv[4] = {v.x, v.y, v.z, v.w};
#pragma unroll
            for (int k = 0; k < 4; ++k) {
                const int j = i * 4 + k;
                const float x = vv[k];
                rv[j] = x;
                sum_all += x;
                if (j == idx0) rs = x;
                if (j == idx1) re = x;
                // jnp.round is half-to-even: for x in [0,1), round==1 <=> x>0.5
                const uint64_t bit = (x > 0.5f) ? 1ull : 0ull;
                if (j < 50) mlo |= bit << j; else mhi |= bit << (j - 50);
                const int delta = ady[j / 10] + adx[j % 10];
                single_cell += (delta == 0) ? (1.f - x) * 20.f
                                            : x * (float)delta * 0.5f;
            }
        }

        // ---- 8-connected flood fill on a 100-bit bitboard (rows of 10 bits) ----
        const uint64_t M50 = (1ull << 50) - 1;
        const uint64_t C0  = 0x10040100401ull;        // column-0 bit of each of 5 rows
        const uint64_t NC0 = M50 & ~C0;               // clear col0 after <<1
        const uint64_t NC9 = M50 & ~(C0 << 9);        // clear col9 after >>1
        uint64_t clo = 0, chi = 0;                    // cluster (seed always set)
        if (idx0 < 50) clo = 1ull << idx0; else chi = 1ull << (idx0 - 50);
#pragma unroll 1
        for (int it = 0; it < GH + GW; ++it) {        // monotone: early exit == 20 iters
            const uint64_t hlo = clo | ((clo << 1) & NC0) | ((clo >> 1) & NC9);
            const uint64_t hhi = chi | ((chi << 1) & NC0) | ((chi >> 1) & NC9);
            uint64_t nlo = (hlo | (hlo << 10) | (hlo >> 10) | ((hhi & 0x3FFull) << 40)) & mlo;
            uint64_t nhi = (hhi | (hhi << 10) | (hhi >> 10) | (hlo >> 40)) & mhi;
            nlo |= clo; nhi |= chi;
            if (nlo == clo && nhi == chi) break;
            clo = nlo; chi = nhi;
        }

        const int K = __popcll(clo) + __popcll(chi);

        // ---- argmin over cluster cells of dist-to-end, first-flat-index ties ----
        int bestd = 1000, bidx = 0;
#pragma unroll
        for (int y = 0; y < GH; ++y) {
            const uint32_t rb = (uint32_t)((y < 5 ? (clo >> (10 * y))
                                                  : (chi >> (10 * (y - 5)))) & 0x3FFull);
            const uint32_t left  = rb & ((2u << p1x) - 1);   // cols 0..p1x
            const uint32_t right = rb >> p1x;                // bit0 = col p1x
            const int dl = left  ? (p1x - (31 - __builtin_clz(left))) : 1000;
            const int dr = right ? __builtin_ctz(right) : 1000;
            int dx, xx;
            if (dl <= dr) { dx = dl; xx = p1x - dl; }        // tie -> smaller col
            else          { dx = dr; xx = p1x + dr; }
            const int d = abs(y - p1y) + dx;
            if (rb && d < bestd) { bestd = d; bidx = y * GW + xx; } // tie -> smaller row
        }

        const bool better = bestd < base;
        const int ny = better ? bidx / 10 : p0y;
        const int nx = better ? bidx % 10 : p0x;
        const int gap = min(base, bestd);

        int by = ny, bx = nx, bg = gap;
        const int oy = p1y - ny, ox = p1x - nx;
        auto upd = [&](bool cond, int cy, int cx) {
            const int d = abs(cy - p1y) + abs(cx - p1x);
            if (cond && (d < bg)) { by = cy; bx = cx; bg = d; }
        };
        upd(ox < 0,                    ny,     nx - 1);
        upd((ox < 0) && (ny != 0),     ny - 1, nx - 1);
        upd((ox < 0) && (ny != GH - 1),ny + 1, nx - 1);
        upd(ox > 0,                    ny,     nx + 1);
        upd((ox > 0) && (ny != 0),     ny - 1, nx + 1);
        upd((ox > 0) && (ny != GH - 1),ny + 1, nx + 1);
        upd(oy < 0,                    ny - 1, nx);
        upd(oy > 0,                    ny + 1, nx);
        const int ncy = min(max(by, 0), GH - 1);
        const int ncx = min(max(bx, 0), GW - 1);
        const int flatn = ncy * GW + ncx;

        // ---- pass 2: transposed-cluster weighted sum + rn select (all regs) ----
        float S_T = 0.f, rn = 0.f;
#pragma unroll
        for (int b = 0; b < 100; ++b) {
            const bool bit = (((b < 50 ? (clo >> b) : (chi >> (b - 50)))) & 1ull) != 0;
            const int tj = (b % 10) * 10 + (b / 10);   // bijective over 0..99
            const float x = rv[tj];
            if (bit) S_T += x;
            if (tj == flatn) rn = x;
        }

        const float csf = (float)K;
        const float loss_start = (2.f - (rs + re)) * 1000.f;
        // lonelyness + cluster_size_pen, algebraically collapsed:
        const float lon  = 5.f * csf + 15.f * sum_all - 20.f * S_T;
        const float cpen = 12.f * csf * S_T;
        const float gap_pen = (float)gap * 300.f * (1.f - rn);
        loss = loss_start + lon + single_cell + cpen + gap_pen;
    }

    // ---- block reduction: wave shuffle -> LDS -> one atomic per block ----
#pragma unroll
    for (int off = 32; off > 0; off >>= 1)
        loss += __shfl_down(loss, off);
    __shared__ float wsum[4];
    const int lane = threadIdx.x & 63;
    const int wid = threadIdx.x >> 6;
    if (lane == 0) wsum[wid] = loss;
    __syncthreads();
    if (threadIdx.x == 0)
        atomicAdd(out, wsum[0] + wsum[1] + wsum[2] + wsum[3]);
}

extern "C" void kernel_launch(void* const* d_in, const int* in_sizes, int n_in,
                              void* d_out, int out_size, void* d_ws, size_t ws_size,
                              hipStream_t stream)
{
    const float* result = (const float*)d_in[0];
    const int* points   = (const int*)d_in[1];
    float* out = (float*)d_out;
    const int B = in_sizes[0] / 100;
    hipMemsetAsync(out, 0, sizeof(float), stream);   // harness poisons d_out with 0xAA
    const int block = 256;
    const int grid = (B + block - 1) / block;
    custom_loss_kernel<<<grid, block, 0, stream>>>(result, points, out, B);
}